// Round 19
// baseline (128.738 us; speedup 1.0000x reference)
//
#include <hip/hip_runtime.h>
#include <math.h>

#define BB 8
#define HWH (512*512)
#define NID 15
#define NSEG (BB*NID)
#define NBINS 256
#define AAF ((float)NBINS/13.0f)
#define LOG2E 1.442695041f
#define LN2 0.6931471806f
#define SLICES 128
#define HSZ (NID*NBINS)

typedef unsigned int uint32;
typedef unsigned long long uint64;

__device__ __forceinline__ float ftanh(float x){
    float t = __expf(2.0f*x);
    return 1.0f - 2.0f*__builtin_amdgcn_rcpf(t + 1.0f);
}
__device__ __forceinline__ float fsigmoid(float x){
    return __builtin_amdgcn_rcpf(1.0f + __expf(-x));
}
__device__ __forceinline__ float sconst(float x){
    return __uint_as_float(__builtin_amdgcn_readfirstlane(__float_as_uint(x)));
}

// ---- phase1f: per-chunk id-stats + focal/bgseed; zero hist/out/part2f ----
__global__ __launch_bounds__(256, 8) void phase1f(const float* __restrict__ pred,
        const int* __restrict__ labels, const int* __restrict__ inst,
        uint64* __restrict__ pstat64, float* __restrict__ pstatf,
        float* __restrict__ pstatf2,
        float* __restrict__ bgseed_p, float* __restrict__ focal_p,
        uint64* __restrict__ Hzero, float* __restrict__ part2f,
        float* __restrict__ out){
    int blk = blockIdx.x;            // 2048 blocks, 256 per image
    int b = blk >> 8;
    int t = threadIdx.x;
    int q = (blk & 255)*256 + t;     // float4 index in image

    if (t < 15) Hzero[blk*15 + t] = 0ull;
    if (blk == 0 && t == 16) out[0] = 0.0f;
    if (blk == 1 && t < NSEG) part2f[t] = 0.0f;

    __shared__ uint64 s64[NID];
    __shared__ float ssig[NID], ssig2[NID];
    __shared__ float wfb[4][2];
    if (t < NID){ s64[t] = 0ull; ssig[t] = 0.0f; ssig2[t] = 0.0f; }
    __syncthreads();

    const int Q = HWH/4;
    const float4* P = (const float4*)(pred + (size_t)b*6*HWH);
    const int4* L = (const int4*)(labels + (size_t)b*3*HWH);
    const int4* I = (const int4*)(inst + (size_t)b*HWH);
    float4 sg4 = P[2*Q+q], z3 = P[3*Q+q], z4 = P[4*Q+q], z5 = P[5*Q+q];
    int4 id4 = I[q];
    int4 l0 = L[q], l1 = L[Q+q], l2 = L[2*Q+q];
    int p = q*4;
    int w0 = p & 511, h0 = p >> 9;

    float facc = 0.0f, bacc = 0.0f;
    auto px = [&](float sgv, float z3v, float z4v, float z5v, int id,
                  int L0, int L1, int L2, int wv){
        float seed = fsigmoid(z5v);
        if (L2 == 0) bacc += seed*seed;
        int tc = 0, best = L0;
        if (L1 > best){ tc = 1; best = L1; }
        if (L2 > best){ tc = 2; }
        float m = fmaxf(z3v, fmaxf(z4v, z5v));
        float e3 = __expf(z3v-m), e4 = __expf(z4v-m), e5 = __expf(z5v-m);
        float sum = e3+e4+e5;
        float lse = m + __logf(sum);
        float zt = (tc==0) ? z3v : ((tc==1) ? z4v : z5v);
        float et = (tc==0) ? e3  : ((tc==1) ? e4  : e5);
        float lp = zt - lse;
        float pt = et*__builtin_amdgcn_rcpf(sum);
        float om = 1.0f - pt;
        facc -= om*om*lp;
        if (id > 0){
            atomicAdd(&s64[id-1],
                      (1ull<<42) | ((uint64)(uint32)wv<<21) | (uint64)(uint32)h0);
            atomicAdd(&ssig[id-1], sgv);
            atomicAdd(&ssig2[id-1], sgv*sgv);
        }
    };
    px(sg4.x, z3.x, z4.x, z5.x, id4.x, l0.x, l1.x, l2.x, w0);
    px(sg4.y, z3.y, z4.y, z5.y, id4.y, l0.y, l1.y, l2.y, w0+1);
    px(sg4.z, z3.z, z4.z, z5.z, id4.z, l0.z, l1.z, l2.z, w0+2);
    px(sg4.w, z3.w, z4.w, z5.w, id4.w, l0.w, l1.w, l2.w, w0+3);

    for (int o = 32; o; o >>= 1){
        facc += __shfl_xor(facc, o);
        bacc += __shfl_xor(bacc, o);
    }
    if ((t & 63) == 0){ wfb[t>>6][0] = facc; wfb[t>>6][1] = bacc; }
    __syncthreads();
    if (t < NID){
        pstat64[blk*16 + t] = s64[t];
        pstatf [blk*16 + t] = ssig[t];
        pstatf2[blk*16 + t] = ssig2[t];
    }
    if (t == 0){
        focal_p[blk]  = wfb[0][0]+wfb[1][0]+wfb[2][0]+wfb[3][0];
        bgseed_p[blk] = wfb[0][1]+wfb[1][1]+wfb[2][1]+wfb[3][1];
    }
}

// ---- phaseR: reduce partials -> stats, derived, var_sum, nobj; focal/bgseed -> out ----
__global__ __launch_bounds__(512) void phaseR(const uint64* __restrict__ pstat64,
        const float* __restrict__ pstatf, const float* __restrict__ pstatf2,
        const float* __restrict__ focal_p, const float* __restrict__ bgseed_p,
        float* __restrict__ stats, float* __restrict__ derived,
        float* __restrict__ results, float* __restrict__ nobjR,
        float* __restrict__ out){
    int b = blockIdx.x;              // 8 blocks
    int t = threadIdx.x;
    int k = t & 15, chunk = t >> 4;
    float acnt = 0, asw = 0, ash = 0, af = 0, af2 = 0;
    for (int i = 0; i < 8; i++){
        int blk = b*256 + chunk*8 + i;
        uint64 v = pstat64[blk*16 + k];
        acnt += (float)(uint32)(v >> 42);
        asw  += (float)(uint32)((v >> 21) & 0x1FFFFF);
        ash  += (float)(uint32)(v & 0x1FFFFF);
        af   += pstatf[blk*16 + k];
        af2  += pstatf2[blk*16 + k];
    }
    __shared__ float tc[16], tw[16], th[16], ts[16], ts2[16];
    if (t < 16){ tc[t]=0; tw[t]=0; th[t]=0; ts[t]=0; ts2[t]=0; }
    __syncthreads();
    atomicAdd(&tc[k], acnt);
    atomicAdd(&tw[k], asw);
    atomicAdd(&th[k], ash);
    atomicAdd(&ts[k], af);
    atomicAdd(&ts2[k], af2);
    __syncthreads();
    if (t < NID){
        float cnt = tc[t];
        float safe = fmaxf(cnt, 1.0f);
        float inv = 1.0f/safe;
        const float SC = 2.0f/511.0f;
        derived[(b*NID+t)*4+0] = tw[t]*SC*inv;
        derived[(b*NID+t)*4+1] = th[t]*SC*inv;
        float sm = ts[t]*inv;
        derived[(b*NID+t)*4+2] = __expf(10.0f*sm);
        derived[(b*NID+t)*4+3] = sm;
        stats[b*60 + t*4] = cnt;
        results[(size_t)(b*NID+t)*3 + 1] = ts2[t] - cnt*sm*sm;
    }
    if (t == NID){
        float nv = 0.0f;
        for (int j = 0; j < NID; j++) nv += (tc[j] > 0.0f) ? 1.0f : 0.0f;
        nobjR[b] = fmaxf(nv, 1.0f);
    }
    int w = t >> 6, lane = t & 63;
    if (w == 0){
        float f = 0;
        for (int j = 0; j < 4; j++) f += focal_p[b*256 + j*64 + lane];
        for (int o = 32; o; o >>= 1) f += __shfl_xor(f, o);
        if (lane == 0) atomicAdd(out, f/(float)(BB*HWH));
    } else if (w == 1){
        float g = 0;
        for (int j = 0; j < 4; j++) g += bgseed_p[b*256 + j*64 + lane];
        for (int o = 32; o; o >>= 1) g += __shfl_xor(g, o);
        if (lane == 0) atomicAdd(out, g/(float)(BB*HWH));
    }
}

// ---- phaseLH: quad bin-merge (4 adjacent px -> 1-2 LDS atomics per k) ----
__global__ __launch_bounds__(512, 6) void phaseLH(const float* __restrict__ pred,
        const int* __restrict__ inst, const float* __restrict__ derived,
        uint64* __restrict__ Hcg, float* __restrict__ part2f){
    int idx = blockIdx.x;
    int b = idx & 7;                 // XCD affinity
    int sp = idx >> 3;
    int t = threadIdx.x;
    int lane = t & 63, w = t >> 6;

    __shared__ __align__(16) uint32 hist[HSZ];   // (count<<16)|fg, 15 KB
    __shared__ float ssl[NID];
    __shared__ float vsB[NID];
    {
        uint4* hz = (uint4*)hist;
        for (int i = t; i < HSZ/4; i += 512) hz[i] = make_uint4(0,0,0,0);
    }
    if (t < NID){
        ssl[t] = derived[(size_t)(b*NID + t)*4 + 2];
        vsB[t] = 0.0f;
    }
    float kcx[NID], kcy[NID], kcs[NID];
    #pragma unroll
    for (int j = 0; j < NID; j++){
        const float* d0 = derived + (size_t)(b*NID + j)*4;
        kcx[j] = sconst(d0[0]);
        kcy[j] = sconst(d0[1]);
        kcs[j] = sconst(LOG2E*AAF*d0[2]);
    }
    __syncthreads();

    const int Q = HWH/4;
    int q0 = sp * (Q / SLICES);      // 512 float4 per block
    const float* pb = pred + (size_t)b*6*HWH;
    const float4* P0 = (const float4*)pb;
    const float4* P1 = P0 + Q;
    const float* z5p = pb + 5*HWH;
    const int4* I = (const int4*)(inst + (size_t)b*HWH);
    const float SC = 2.0f/511.0f;

    // lane-decorrelated assignment: adjacent lanes 2 float4s (8 px) apart
    int q = q0 + lane*2 + (w & 1) + (w >> 1)*128;
    int4 id4 = I[q];
    float4 a = P0[q], c = P1[q];
    int p = q*4;
    float gx = (float)(p & 511)*SC;
    float gy = (float)(p >> 9)*SC;   // 4 px share one row
    float ex0 = ftanh(a.x) + gx;
    float ex1 = ftanh(a.y) + gx + SC;
    float ex2 = ftanh(a.z) + gx + 2.0f*SC;
    float ex3 = ftanh(a.w) + gx + 3.0f*SC;
    float ey0 = ftanh(c.x) + gy;
    float ey1 = ftanh(c.y) + gy;
    float ey2 = ftanh(c.z) + gy;
    float ey3 = ftanh(c.w) + gy;
    int own0 = id4.x - 1, own1 = id4.y - 1, own2 = id4.z - 1, own3 = id4.w - 1;
    float r2o0 = 0, r2o1 = 0, r2o2 = 0, r2o3 = 0;
    int bo0 = -1, bo1 = -1, bo2 = -1, bo3 = -1;

    #pragma unroll
    for (int j = 0; j < NID; j++){
        float dx0 = ex0 - kcx[j], dy0 = ey0 - kcy[j];
        float dx1 = ex1 - kcx[j], dy1 = ey1 - kcy[j];
        float dx2 = ex2 - kcx[j], dy2 = ey2 - kcy[j];
        float dx3 = ex3 - kcx[j], dy3 = ey3 - kcy[j];
        float r20 = fmaf(dx0, dx0, dy0*dy0);
        float r21 = fmaf(dx1, dx1, dy1*dy1);
        float r22 = fmaf(dx2, dx2, dy2*dy2);
        float r23 = fmaf(dx3, dx3, dy3*dy3);
        float f0 = fminf(fmaf(-kcs[j], r20, (float)NBINS), (float)(NBINS-1));
        float f1 = fminf(fmaf(-kcs[j], r21, (float)NBINS), (float)(NBINS-1));
        float f2 = fminf(fmaf(-kcs[j], r22, (float)NBINS), (float)(NBINS-1));
        float f3 = fminf(fmaf(-kcs[j], r23, (float)NBINS), (float)(NBINS-1));
        int b0 = (f0 >= 1.0f) ? (int)f0 : -1;
        int b1 = (f1 >= 1.0f) ? (int)f1 : -1;
        int b2 = (f2 >= 1.0f) ? (int)f2 : -1;
        int b3 = (f3 >= 1.0f) ? (int)f3 : -1;
        if (j == own0){ r2o0 = r20; bo0 = b0; }
        if (j == own1){ r2o1 = r21; bo1 = b1; }
        if (j == own2){ r2o2 = r22; bo2 = b2; }
        if (j == own3){ r2o3 = r23; bo3 = b3; }
        // register merge of equal bins -> fewer LDS atomics
        uint32 add0 = 65536u, add1 = 65536u, add2 = 65536u, add3 = 65536u;
        if (b1 == b0){ add0 += 65536u; add1 = 0u; }
        if (b2 == b0){ add0 += 65536u; add2 = 0u; }
        else if (add1 && b2 == b1){ add1 += 65536u; add2 = 0u; }
        if (b3 == b0){ add0 += 65536u; add3 = 0u; }
        else if (add1 && b3 == b1){ add1 += 65536u; add3 = 0u; }
        else if (add2 && b3 == b2){ add2 += 65536u; add3 = 0u; }
        uint32* kb = &hist[j*NBINS];
        if (b0 >= 0) atomicAdd(&kb[b0], add0);
        if (add1 && b1 >= 0) atomicAdd(&kb[b1], add1);
        if (add2 && b2 >= 0) atomicAdd(&kb[b2], add2);
        if (add3 && b3 >= 0) atomicAdd(&kb[b3], add3);
    }
    // fg fixup per pixel: undo captured bg bin, insert fg bin, seed accum
    auto fg = [&](int own, float r2o, int bo, int pi){
        if (own >= 0){
            if (bo >= 0) atomicAdd(&hist[own*NBINS + bo], 0xFFFF0000u);
            float s = ssl[own];
            float d = __expf(-s*r2o);
            float e = fmaf(-2.0f, d, 2.0f);
            float bf = fmaf(__log2f(e), AAF, (float)NBINS - AAF);
            bf = fminf(fmaxf(bf, 0.0f), (float)(NBINS-1));
            atomicAdd(&hist[own*NBINS + (int)bf], 65537u);
            float seed = fsigmoid(z5p[pi]);
            float sd = seed - d;
            atomicAdd(&vsB[own], sd*sd);
        }
    };
    fg(own0, r2o0, bo0, p);
    fg(own1, r2o1, bo1, p+1);
    fg(own2, r2o2, bo2, p+2);
    fg(own3, r2o3, bo3, p+3);

    __syncthreads();
    // sparse PACKED u64 atomic accumulation into final histograms (L2-resident)
    size_t base = (size_t)b*HSZ;
    for (int i = t; i < HSZ; i += 512){
        uint32 v = hist[i];
        if (v){
            uint64 pk = ((uint64)(v >> 16) << 32) | (uint64)(v & 0xFFFFu);
            atomicAdd(&Hcg[base + i], pk);
        }
    }
    if (t < NID && vsB[t] != 0.0f)
        atomicAdd(&part2f[b*NID + t], vsB[t]);
}

// ---- phaseLS: descending Lovasz scan with derived bin-0; fused final combine ----
__global__ __launch_bounds__(256) void phaseLS(const uint64* __restrict__ Hcg,
        const float* __restrict__ part2f,
        const float* __restrict__ stats, const float* __restrict__ results,
        const float* __restrict__ nobjR, float* __restrict__ out){
    int idx = blockIdx.x;            // 120
    int b = idx & 7, k = idx >> 3;
    int seg = b*NID + k;
    int t = threadIdx.x;             // 256

    __shared__ uint32 wbc[4], wbg[4], wexc[4], wexg[4];
    __shared__ float wsum[4];

    size_t base = (size_t)seg*NBINS;
    uint64 pk = Hcg[base + NBINS-1-t];
    uint32 cd = (uint32)(pk >> 32);
    uint32 gd = (uint32)(pk & 0xFFFFFFFFull);
    uint32 ci = cd, gi2 = gd;
    int lane = t & 63, w = t >> 6;
    for (int o = 1; o < 64; o <<= 1){
        uint32 cu = __shfl_up(ci, o);
        uint32 gu = __shfl_up(gi2, o);
        if (lane >= o){ ci += cu; gi2 += gu; }
    }
    if (lane == 63){ wbc[w] = ci; wbg[w] = gi2; }
    __syncthreads();
    if (t == 0){
        uint32 rc = 0, rg = 0;
        for (int i = 0; i < 4; i++){
            uint32 a = wbc[i], bq = wbg[i];
            wexc[i] = rc; wexg[i] = rg;
            rc += a; rg += bq;
        }
    }
    __syncthreads();

    float G = stats[b*60 + k*4];
    uint32 cd_use = cd;
    if (t == NBINS-1){
        uint32 totalRaw = wexc[3] + wbc[3];
        cd_use = cd + ((uint32)HWH - totalRaw);
    }
    float contrib = 0.0f;
    if (G > 0.0f && (cd_use | gd)){
        uint32 nb = wexc[w] + (ci - cd);
        uint32 gb = wexg[w] + (gi2 - gd);
        float jp = 0.0f;
        if (nb > 0) jp = 1.0f - (G - (float)gb)/(G + (float)(nb - gb));
        uint32 n = nb + cd_use, gg = gb + gd;
        float j2 = 1.0f - (G - (float)gg)/(G + (float)(n - gg));
        int bin = NBINS-1-t;
        float ev = __expf(LN2*(((float)bin + 0.5f)*(13.0f/(float)NBINS) - 12.0f));
        contrib = ev*(j2 - jp);
    }
    for (int o = 32; o; o >>= 1) contrib += __shfl_xor(contrib, o);
    if (lane == 0) wsum[w] = contrib;
    __syncthreads();
    if (t == 0 && G > 0.0f){
        float lov = wsum[0]+wsum[1]+wsum[2]+wsum[3];
        float nobj = nobjR[b];
        float var = results[(size_t)seg*3 + 1];
        float seedsum = part2f[seg];
        float val = (lov + 10.0f*var/G)/(nobj*(float)BB)
                  + seedsum/((float)HWH*(float)BB);
        atomicAdd(out, val);
    }
}

extern "C" void kernel_launch(void* const* d_in, const int* in_sizes, int n_in,
                              void* d_out, int out_size, void* d_ws, size_t ws_size,
                              hipStream_t stream){
    const float* pred  = (const float*)d_in[0];
    const int*   labels= (const int*)d_in[1];
    const int*   inst  = (const int*)d_in[2];
    float* out = (float*)d_out;

    uint64* Hcg    = (uint64*)d_ws;                          // NSEG*NBINS u64
    float* part2f  = (float*)(Hcg + (size_t)NSEG*NBINS);     // NSEG (pad 128)
    uint64* pstat64= (uint64*)(part2f + 128);                // 2048*16
    float* pstatf  = (float*)(pstat64 + 2048*16);
    float* pstatf2 = pstatf + 2048*16;
    float* focal_p = pstatf2 + 2048*16;
    float* bgseed_p= focal_p + 2048;
    float* stats   = bgseed_p + 2048;
    float* derived = stats + 480;
    float* results = derived + 480;
    float* nobjR   = results + 360;

    hipLaunchKernelGGL(phase1f, dim3(2048), dim3(256), 0, stream,
                       pred, labels, inst, pstat64, pstatf, pstatf2,
                       bgseed_p, focal_p, Hcg, part2f, out);
    hipLaunchKernelGGL(phaseR, dim3(8), dim3(512), 0, stream,
                       pstat64, pstatf, pstatf2, focal_p, bgseed_p,
                       stats, derived, results, nobjR, out);
    hipLaunchKernelGGL(phaseLH, dim3(BB*SLICES), dim3(512), 0, stream,
                       pred, inst, derived, Hcg, part2f);
    hipLaunchKernelGGL(phaseLS, dim3(NSEG), dim3(256), 0, stream,
                       Hcg, part2f, stats, results, nobjR, out);
}

// Round 20
// 74.613 us; speedup vs baseline: 1.7254x; 1.7254x over previous
//
#include <hip/hip_runtime.h>
#include <math.h>

#define BB 8
#define HWH (512*512)
#define NID 15
#define NSEG (BB*NID)
#define NBINS 256
#define AAF ((float)NBINS/13.0f)
#define LOG2E 1.442695041f
#define LN2 0.6931471806f
#define SLICES 128

typedef unsigned int uint32;
typedef unsigned long long uint64;

__device__ __forceinline__ float ftanh(float x){
    float t = __expf(2.0f*x);
    return 1.0f - 2.0f*__builtin_amdgcn_rcpf(t + 1.0f);
}
__device__ __forceinline__ float fsigmoid(float x){
    return __builtin_amdgcn_rcpf(1.0f + __expf(-x));
}
__device__ __forceinline__ float sconst(float x){
    return __uint_as_float(__builtin_amdgcn_readfirstlane(__float_as_uint(x)));
}

// ---- phase1f: per-chunk id-stats + focal/bgseed; zero hist/out/part2f ----
__global__ __launch_bounds__(256, 8) void phase1f(const float* __restrict__ pred,
        const int* __restrict__ labels, const int* __restrict__ inst,
        uint64* __restrict__ pstat64, float* __restrict__ pstatf,
        float* __restrict__ pstatf2,
        float* __restrict__ bgseed_p, float* __restrict__ focal_p,
        uint32* __restrict__ Hzero, float* __restrict__ part2f,
        float* __restrict__ out){
    int blk = blockIdx.x;            // 2048 blocks, 256 per image
    int b = blk >> 8;
    int t = threadIdx.x;
    int q = (blk & 255)*256 + t;     // float4 index in image

    // distributed zeroing of the final histograms (2*NSEG*NBINS = 2048*30 words)
    if (t < 30) Hzero[blk*30 + t] = 0u;
    if (blk == 0 && t == 30) out[0] = 0.0f;
    if (blk == 1 && t < NSEG) part2f[t] = 0.0f;

    __shared__ uint64 s64[NID];
    __shared__ float ssig[NID], ssig2[NID];
    __shared__ float wfb[4][2];
    if (t < NID){ s64[t] = 0ull; ssig[t] = 0.0f; ssig2[t] = 0.0f; }
    __syncthreads();

    const int Q = HWH/4;
    const float4* P = (const float4*)(pred + (size_t)b*6*HWH);
    const int4* L = (const int4*)(labels + (size_t)b*3*HWH);
    const int4* I = (const int4*)(inst + (size_t)b*HWH);
    float4 sg4 = P[2*Q+q], z3 = P[3*Q+q], z4 = P[4*Q+q], z5 = P[5*Q+q];
    int4 id4 = I[q];
    int4 l0 = L[q], l1 = L[Q+q], l2 = L[2*Q+q];
    int p = q*4;
    int w0 = p & 511, h0 = p >> 9;

    float facc = 0.0f, bacc = 0.0f;
    auto px = [&](float sgv, float z3v, float z4v, float z5v, int id,
                  int L0, int L1, int L2, int wv){
        float seed = fsigmoid(z5v);
        if (L2 == 0) bacc += seed*seed;
        int tc = 0, best = L0;
        if (L1 > best){ tc = 1; best = L1; }
        if (L2 > best){ tc = 2; }
        float m = fmaxf(z3v, fmaxf(z4v, z5v));
        float e3 = __expf(z3v-m), e4 = __expf(z4v-m), e5 = __expf(z5v-m);
        float sum = e3+e4+e5;
        float lse = m + __logf(sum);
        float zt = (tc==0) ? z3v : ((tc==1) ? z4v : z5v);
        float et = (tc==0) ? e3  : ((tc==1) ? e4  : e5);
        float lp = zt - lse;
        float pt = et*__builtin_amdgcn_rcpf(sum);
        float om = 1.0f - pt;
        facc -= om*om*lp;
        if (id > 0){
            atomicAdd(&s64[id-1],
                      (1ull<<42) | ((uint64)(uint32)wv<<21) | (uint64)(uint32)h0);
            atomicAdd(&ssig[id-1], sgv);
            atomicAdd(&ssig2[id-1], sgv*sgv);
        }
    };
    px(sg4.x, z3.x, z4.x, z5.x, id4.x, l0.x, l1.x, l2.x, w0);
    px(sg4.y, z3.y, z4.y, z5.y, id4.y, l0.y, l1.y, l2.y, w0+1);
    px(sg4.z, z3.z, z4.z, z5.z, id4.z, l0.z, l1.z, l2.z, w0+2);
    px(sg4.w, z3.w, z4.w, z5.w, id4.w, l0.w, l1.w, l2.w, w0+3);

    for (int o = 32; o; o >>= 1){
        facc += __shfl_xor(facc, o);
        bacc += __shfl_xor(bacc, o);
    }
    if ((t & 63) == 0){ wfb[t>>6][0] = facc; wfb[t>>6][1] = bacc; }
    __syncthreads();
    if (t < NID){
        pstat64[blk*16 + t] = s64[t];
        pstatf [blk*16 + t] = ssig[t];
        pstatf2[blk*16 + t] = ssig2[t];
    }
    if (t == 0){
        focal_p[blk]  = wfb[0][0]+wfb[1][0]+wfb[2][0]+wfb[3][0];
        bgseed_p[blk] = wfb[0][1]+wfb[1][1]+wfb[2][1]+wfb[3][1];
    }
}

// ---- phaseR: reduce partials -> stats, derived, var_sum, nobj; focal/bgseed -> out ----
__global__ __launch_bounds__(512) void phaseR(const uint64* __restrict__ pstat64,
        const float* __restrict__ pstatf, const float* __restrict__ pstatf2,
        const float* __restrict__ focal_p, const float* __restrict__ bgseed_p,
        float* __restrict__ stats, float* __restrict__ derived,
        float* __restrict__ results, float* __restrict__ nobjR,
        float* __restrict__ out){
    int b = blockIdx.x;              // 8 blocks
    int t = threadIdx.x;
    int k = t & 15, chunk = t >> 4;  // 32 chunks x 8 partial-blocks
    float acnt = 0, asw = 0, ash = 0, af = 0, af2 = 0;
    for (int i = 0; i < 8; i++){
        int blk = b*256 + chunk*8 + i;
        uint64 v = pstat64[blk*16 + k];
        acnt += (float)(uint32)(v >> 42);
        asw  += (float)(uint32)((v >> 21) & 0x1FFFFF);
        ash  += (float)(uint32)(v & 0x1FFFFF);
        af   += pstatf[blk*16 + k];
        af2  += pstatf2[blk*16 + k];
    }
    __shared__ float tc[16], tw[16], th[16], ts[16], ts2[16];
    if (t < 16){ tc[t]=0; tw[t]=0; th[t]=0; ts[t]=0; ts2[t]=0; }
    __syncthreads();
    atomicAdd(&tc[k], acnt);
    atomicAdd(&tw[k], asw);
    atomicAdd(&th[k], ash);
    atomicAdd(&ts[k], af);
    atomicAdd(&ts2[k], af2);
    __syncthreads();
    if (t < NID){
        float cnt = tc[t];
        float safe = fmaxf(cnt, 1.0f);
        float inv = 1.0f/safe;
        const float SC = 2.0f/511.0f;
        derived[(b*NID+t)*4+0] = tw[t]*SC*inv;
        derived[(b*NID+t)*4+1] = th[t]*SC*inv;
        float sm = ts[t]*inv;
        derived[(b*NID+t)*4+2] = __expf(10.0f*sm);
        derived[(b*NID+t)*4+3] = sm;
        stats[b*60 + t*4] = cnt;
        results[(size_t)(b*NID+t)*3 + 1] = ts2[t] - cnt*sm*sm;
    }
    if (t == NID){
        float nv = 0.0f;
        for (int j = 0; j < NID; j++) nv += (tc[j] > 0.0f) ? 1.0f : 0.0f;
        nobjR[b] = fmaxf(nv, 1.0f);
    }
    int w = t >> 6, lane = t & 63;
    if (w == 0){
        float f = 0;
        for (int j = 0; j < 4; j++) f += focal_p[b*256 + j*64 + lane];
        for (int o = 32; o; o >>= 1) f += __shfl_xor(f, o);
        if (lane == 0) atomicAdd(out, f/(float)(BB*HWH));
    } else if (w == 1){
        float g = 0;
        for (int j = 0; j < 4; j++) g += bgseed_p[b*256 + j*64 + lane];
        for (int o = 32; o; o >>= 1) g += __shfl_xor(g, o);
        if (lane == 0) atomicAdd(out, g/(float)(BB*HWH));
    }
}

// ---- phaseLH: lane-decorrelated pixels; branchless bg loop; captured-bin undo ----
__global__ __launch_bounds__(512, 8) void phaseLH(const float* __restrict__ pred,
        const int* __restrict__ inst, const float* __restrict__ derived,
        uint32* __restrict__ Hc, uint32* __restrict__ Hg,
        float* __restrict__ part2f){
    int idx = blockIdx.x;
    int b = idx & 7;                 // XCD affinity
    int sp = idx >> 3;
    int t = threadIdx.x;
    int lane = t & 63, w = t >> 6;

    __shared__ __align__(16) uint32 hist[NID*NBINS];   // (count<<16)|fg, 15 KB
    __shared__ float ssl[NID];
    __shared__ float vsB[NID];
    {
        uint4* hz = (uint4*)hist;
        for (int i = t; i < NID*NBINS/4; i += 512) hz[i] = make_uint4(0,0,0,0);
    }
    if (t < NID){
        ssl[t] = derived[(size_t)(b*NID + t)*4 + 2];
        vsB[t] = 0.0f;
    }
    float kcx[NID], kcy[NID], kcs[NID];
    #pragma unroll
    for (int j = 0; j < NID; j++){
        const float* d0 = derived + (size_t)(b*NID + j)*4;
        kcx[j] = sconst(d0[0]);
        kcy[j] = sconst(d0[1]);
        kcs[j] = sconst(LOG2E*AAF*d0[2]);
    }
    __syncthreads();

    const int Q = HWH/4;
    const int qps = Q / SLICES;      // 512 float4 per block
    int q0 = sp * qps;
    const float* pb = pred + (size_t)b*6*HWH;
    const float4* P0 = (const float4*)pb;
    const float4* P1 = P0 + Q;
    const float* z5p = pb + 5*HWH;
    const int4* I = (const int4*)(inst + (size_t)b*HWH);
    const float SC = 2.0f/511.0f;

    // lane-decorrelated assignment: adjacent lanes 2 float4s (8 px) apart
    int q = q0 + lane*2 + (w & 1) + (w >> 1)*128;
    {
        int4 id4 = I[q];
        float4 a = P0[q], c = P1[q];
        int p = q*4;
        float gx = (float)(p & 511)*SC;
        float gy = (float)(p >> 9)*SC;
        auto px = [&](float av, float cv, int id, float gxv, int pi){
            float ex = ftanh(av) + gxv;
            float ey = ftanh(cv) + gy;
            int own = id - 1;
            float r2own = 0.0f, binf_own = 0.0f;
            #pragma unroll
            for (int j = 0; j < NID; j++){
                float dx = ex - kcx[j], dy = ey - kcy[j];
                float r2 = fmaf(dx, dx, dy*dy);
                float binf = fmaf(-kcs[j], r2, (float)NBINS);
                binf = fminf(binf, (float)(NBINS-1));
                if (j == own){ r2own = r2; binf_own = binf; }   // cndmask captures
                if (binf >= 1.0f)
                    atomicAdd(&hist[j*NBINS + (int)binf], 65536u);
            }
            if (own >= 0){
                if (binf_own >= 1.0f)              // undo EXACTLY the inserted bin
                    atomicAdd(&hist[own*NBINS + (int)binf_own], 0xFFFF0000u);
                float s = ssl[own];
                float d = __expf(-s*r2own);
                float e = fmaf(-2.0f, d, 2.0f);
                float bf = fmaf(__log2f(e), AAF, (float)NBINS - AAF);
                bf = fminf(fmaxf(bf, 0.0f), (float)(NBINS-1));
                atomicAdd(&hist[own*NBINS + (int)bf], 65537u);   // fg entry
                float seed = fsigmoid(z5p[pi]);
                float sd = seed - d;
                atomicAdd(&vsB[own], sd*sd);
            }
        };
        px(a.x, c.x, id4.x, gx,      p);
        px(a.y, c.y, id4.y, gx+SC,   p+1);
        px(a.z, c.z, id4.z, gx+2*SC, p+2);
        px(a.w, c.w, id4.w, gx+3*SC, p+3);
    }
    __syncthreads();
    // sparse atomic accumulation into the final per-segment histograms (L2-resident)
    size_t base = (size_t)b*NID*NBINS;
    for (int i = t; i < NID*NBINS; i += 512){
        uint32 v = hist[i];
        if (v){
            uint32 cc = v >> 16, gg = v & 0xFFFFu;
            if (cc) atomicAdd(&Hc[base + i], cc);
            if (gg) atomicAdd(&Hg[base + i], gg);
        }
    }
    if (t < NID && vsB[t] != 0.0f)
        atomicAdd(&part2f[b*NID + t], vsB[t]);
}

// ---- phaseLS: descending Lovasz scan with derived bin-0; fused final combine ----
__global__ __launch_bounds__(256) void phaseLS(const uint32* __restrict__ Hc,
        const uint32* __restrict__ Hg, const float* __restrict__ part2f,
        const float* __restrict__ stats, const float* __restrict__ results,
        const float* __restrict__ nobjR, float* __restrict__ out){
    int idx = blockIdx.x;            // 120
    int b = idx & 7, k = idx >> 3;
    int seg = b*NID + k;
    int t = threadIdx.x;             // 256

    __shared__ uint32 wbc[4], wbg[4], wexc[4], wexg[4];
    __shared__ float wsum[4];

    size_t base = (size_t)seg*NBINS;
    uint32 cd = Hc[base + NBINS-1-t];       // thread t handles bin NBINS-1-t
    uint32 gd = Hg[base + NBINS-1-t];
    uint32 ci = cd, gi2 = gd;
    int lane = t & 63, w = t >> 6;
    for (int o = 1; o < 64; o <<= 1){
        uint32 cu = __shfl_up(ci, o);
        uint32 gu = __shfl_up(gi2, o);
        if (lane >= o){ ci += cu; gi2 += gu; }
    }
    if (lane == 63){ wbc[w] = ci; wbg[w] = gi2; }
    __syncthreads();
    if (t == 0){
        uint32 rc = 0, rg = 0;
        for (int i = 0; i < 4; i++){
            uint32 a = wbc[i], bq = wbg[i];
            wexc[i] = rc; wexg[i] = rg;
            rc += a; rg += bq;
        }
    }
    __syncthreads();

    float G = stats[b*60 + k*4];
    // bin-0 bg inserts were skipped in phaseLH: derive so totals reach HWH
    uint32 cd_use = cd;
    if (t == NBINS-1){
        uint32 totalRaw = wexc[3] + wbc[3];
        cd_use = cd + ((uint32)HWH - totalRaw);
    }
    float contrib = 0.0f;
    if (G > 0.0f && (cd_use | gd)){
        uint32 nb = wexc[w] + (ci - cd);
        uint32 gb = wexg[w] + (gi2 - gd);
        float jp = 0.0f;
        if (nb > 0) jp = 1.0f - (G - (float)gb)/(G + (float)(nb - gb));
        uint32 n = nb + cd_use, gg = gb + gd;
        float j2 = 1.0f - (G - (float)gg)/(G + (float)(n - gg));
        int bin = NBINS-1-t;
        float ev = __expf(LN2*(((float)bin + 0.5f)*(13.0f/(float)NBINS) - 12.0f));
        contrib = ev*(j2 - jp);
    }
    for (int o = 32; o; o >>= 1) contrib += __shfl_xor(contrib, o);
    if (lane == 0) wsum[w] = contrib;
    __syncthreads();
    if (t == 0 && G > 0.0f){
        float lov = wsum[0]+wsum[1]+wsum[2]+wsum[3];
        float nobj = nobjR[b];
        float var = results[(size_t)seg*3 + 1];
        float seedsum = part2f[seg];
        float val = (lov + 10.0f*var/G)/(nobj*(float)BB)
                  + seedsum/((float)HWH*(float)BB);
        atomicAdd(out, val);
    }
}

extern "C" void kernel_launch(void* const* d_in, const int* in_sizes, int n_in,
                              void* d_out, int out_size, void* d_ws, size_t ws_size,
                              hipStream_t stream){
    const float* pred  = (const float*)d_in[0];
    const int*   labels= (const int*)d_in[1];
    const int*   inst  = (const int*)d_in[2];
    float* out = (float*)d_out;

    uint32* Hc     = (uint32*)d_ws;                          // NSEG*NBINS
    uint32* Hg     = Hc + (size_t)NSEG*NBINS;                // NSEG*NBINS
    float* part2f  = (float*)(Hg + (size_t)NSEG*NBINS);      // NSEG (pad 128)
    uint64* pstat64= (uint64*)(part2f + 128);                // 2048*16
    float* pstatf  = (float*)(pstat64 + 2048*16);
    float* pstatf2 = pstatf + 2048*16;
    float* focal_p = pstatf2 + 2048*16;
    float* bgseed_p= focal_p + 2048;
    float* stats   = bgseed_p + 2048;
    float* derived = stats + 480;
    float* results = derived + 480;
    float* nobjR   = results + 360;

    hipLaunchKernelGGL(phase1f, dim3(2048), dim3(256), 0, stream,
                       pred, labels, inst, pstat64, pstatf, pstatf2,
                       bgseed_p, focal_p, Hc, part2f, out);
    hipLaunchKernelGGL(phaseR, dim3(8), dim3(512), 0, stream,
                       pstat64, pstatf, pstatf2, focal_p, bgseed_p,
                       stats, derived, results, nobjR, out);
    hipLaunchKernelGGL(phaseLH, dim3(BB*SLICES), dim3(512), 0, stream,
                       pred, inst, derived, Hc, Hg, part2f);
    hipLaunchKernelGGL(phaseLS, dim3(NSEG), dim3(256), 0, stream,
                       Hc, Hg, part2f, stats, results, nobjR, out);
}